// Round 2
// 264.930 us; speedup vs baseline: 1.0320x; 1.0320x over previous
//
#include <hip/hip_runtime.h>

#define Bn 4
#define Nn 4096000
#define Kn 409664
#define R0c 3686399u
#define R1c 3686400u

// ws offsets (u32 units)
#define H1_OFF 0          // B*2048
#define H2_OFF 8192       // B*2*2048
#define H3_OFF 24576      // B*2*1024
#define ST_OFF 32768      // B*4  {key/prefix0, rem0, key/prefix1, rem1}
#define CNT_OFF 32784     // B
#define BC_OFF 32788      // B*1000

#define OUT_SP  ((size_t)Bn * Kn * 5)
#define OUT_VAL ((size_t)Bn * Kn * 9)

__device__ __forceinline__ unsigned fkey(float x) {
    unsigned u = __float_as_uint(x);
    return u ^ ((unsigned)((int)u >> 31) | 0x80000000u);
}
__device__ __forceinline__ float keyf(unsigned k) {
    unsigned u = (k & 0x80000000u) ? (k & 0x7FFFFFFFu) : ~k;
    return __uint_as_float(u);
}

// boundary float: smallest float bv such that (double)bv > thr.
// Then ((double)x > thr)  <=>  (x >= bv)  for float x (no NaN in data).
// Successor in monotonic key space replaces nextafterf (no libm dep).
__device__ __forceinline__ float boundary_from_ws(const unsigned* __restrict__ ws, int b) {
    float vlo = keyf(ws[ST_OFF + b * 4 + 0]);
    float vhi = keyf(ws[ST_OFF + b * 4 + 2]);
    double thr = (double)vlo + 0.1 * ((double)vhi - (double)vlo);
    float c = (float)thr;  // round-to-nearest; within 1 ulp of thr
    if ((double)c > thr) return c;
    return keyf(fkey(c) + 1u);  // next float above c in total order
}

// ---------------- histogram pass 1: top 11 bits (per-wave privatized) ----------------
__global__ void hist1_k(const float* __restrict__ cube, unsigned* __restrict__ ws) {
    __shared__ unsigned h[4][2048];
    int tid = threadIdx.x, blk = blockIdx.x;
    int b = blk / 250, c = blk % 250;
    int wid = tid >> 6;
    unsigned* hw = h[wid];
    unsigned* hl = &h[0][0];
    for (int j = tid; j < 8192; j += 256) hl[j] = 0;
    __syncthreads();
    const float4* p = (const float4*)(cube + (size_t)b * Nn + (size_t)c * 16384);
    for (int it = 0; it < 16; ++it) {
        float4 v = p[it * 256 + tid];
        atomicAdd(&hw[fkey(v.x) >> 21], 1u);
        atomicAdd(&hw[fkey(v.y) >> 21], 1u);
        atomicAdd(&hw[fkey(v.z) >> 21], 1u);
        atomicAdd(&hw[fkey(v.w) >> 21], 1u);
    }
    __syncthreads();
    unsigned* g = ws + H1_OFF + b * 2048;
    for (int j = tid; j < 2048; j += 256) {
        unsigned s = h[0][j] + h[1][j] + h[2][j] + h[3][j];
        if (s) atomicAdd(&g[j], s);
    }
}

// ---------------- pick from pass-1 histogram (both ranks) ----------------
__global__ void pick1_k(unsigned* __restrict__ ws) {
    __shared__ unsigned sh[256];
    int tid = threadIdx.x, b = blockIdx.x;
    const unsigned* hist = ws + H1_OFF + b * 2048;
    unsigned loc[8], lsum = 0;
    for (int j = 0; j < 8; ++j) { loc[j] = hist[tid * 8 + j]; lsum += loc[j]; }
    sh[tid] = lsum; __syncthreads();
    for (int off = 1; off < 256; off <<= 1) {
        unsigned v = (tid >= off) ? sh[tid - off] : 0u; __syncthreads();
        sh[tid] += v; __syncthreads();
    }
    unsigned base = tid ? sh[tid - 1] : 0u;
    unsigned ranks[2] = {R0c, R1c};
    for (int pth = 0; pth < 2; ++pth) {
        unsigned r = ranks[pth];
        if (r >= base && r < base + lsum) {
            unsigned cacc = base;
            for (int j = 0; j < 8; ++j) {
                if (r < cacc + loc[j]) {
                    ws[ST_OFF + b * 4 + pth * 2] = (unsigned)(tid * 8 + j);
                    ws[ST_OFF + b * 4 + pth * 2 + 1] = r - cacc;
                    break;
                }
                cacc += loc[j];
            }
        }
    }
}

// ---------------- histogram pass 2: middle 11 bits, two prefix paths ----------------
__global__ void hist2_k(const float* __restrict__ cube, unsigned* __restrict__ ws) {
    __shared__ unsigned h0[2048], h1[2048];
    int tid = threadIdx.x, blk = blockIdx.x;
    int b = blk / 250, c = blk % 250;
    unsigned p0 = ws[ST_OFF + b * 4 + 0];
    unsigned p1 = ws[ST_OFF + b * 4 + 2];
    for (int j = tid; j < 2048; j += 256) { h0[j] = 0; h1[j] = 0; }
    __syncthreads();
    const float4* p = (const float4*)(cube + (size_t)b * Nn + (size_t)c * 16384);
    for (int it = 0; it < 16; ++it) {
        float4 v = p[it * 256 + tid];
        float vv[4] = {v.x, v.y, v.z, v.w};
        for (int q = 0; q < 4; ++q) {
            unsigned k = fkey(vv[q]);
            unsigned top = k >> 21;
            unsigned mid = (k >> 10) & 0x7FFu;
            if (top == p0) atomicAdd(&h0[mid], 1u);
            if (top == p1) atomicAdd(&h1[mid], 1u);
        }
    }
    __syncthreads();
    unsigned* g0 = ws + H2_OFF + (b * 2) * 2048;
    unsigned* g1 = g0 + 2048;
    for (int j = tid; j < 2048; j += 256) {
        if (h0[j]) atomicAdd(&g0[j], h0[j]);
        if (h1[j]) atomicAdd(&g1[j], h1[j]);
    }
}

__global__ void pick2_k(unsigned* __restrict__ ws) {
    __shared__ unsigned sh[256];
    int tid = threadIdx.x; int b = blockIdx.x >> 1, pth = blockIdx.x & 1;
    const unsigned* hist = ws + H2_OFF + (b * 2 + pth) * 2048;
    unsigned r = ws[ST_OFF + b * 4 + pth * 2 + 1];
    unsigned pref = ws[ST_OFF + b * 4 + pth * 2];
    unsigned loc[8], lsum = 0;
    for (int j = 0; j < 8; ++j) { loc[j] = hist[tid * 8 + j]; lsum += loc[j]; }
    sh[tid] = lsum; __syncthreads();
    for (int off = 1; off < 256; off <<= 1) {
        unsigned v = (tid >= off) ? sh[tid - off] : 0u; __syncthreads();
        sh[tid] += v; __syncthreads();
    }
    unsigned base = tid ? sh[tid - 1] : 0u;
    if (r >= base && r < base + lsum) {
        unsigned cacc = base;
        for (int j = 0; j < 8; ++j) {
            if (r < cacc + loc[j]) {
                ws[ST_OFF + b * 4 + pth * 2] = (pref << 11) | (unsigned)(tid * 8 + j);
                ws[ST_OFF + b * 4 + pth * 2 + 1] = r - cacc;
                break;
            }
            cacc += loc[j];
        }
    }
}

// ---------------- histogram pass 3: low 10 bits ----------------
__global__ void hist3_k(const float* __restrict__ cube, unsigned* __restrict__ ws) {
    __shared__ unsigned h0[1024], h1[1024];
    int tid = threadIdx.x, blk = blockIdx.x;
    int b = blk / 250, c = blk % 250;
    unsigned p0 = ws[ST_OFF + b * 4 + 0];
    unsigned p1 = ws[ST_OFF + b * 4 + 2];
    for (int j = tid; j < 1024; j += 256) { h0[j] = 0; h1[j] = 0; }
    __syncthreads();
    const float4* p = (const float4*)(cube + (size_t)b * Nn + (size_t)c * 16384);
    for (int it = 0; it < 16; ++it) {
        float4 v = p[it * 256 + tid];
        float vv[4] = {v.x, v.y, v.z, v.w};
        for (int q = 0; q < 4; ++q) {
            unsigned k = fkey(vv[q]);
            unsigned top = k >> 10;
            unsigned lowb = k & 0x3FFu;
            if (top == p0) atomicAdd(&h0[lowb], 1u);
            if (top == p1) atomicAdd(&h1[lowb], 1u);
        }
    }
    __syncthreads();
    unsigned* g0 = ws + H3_OFF + (b * 2) * 1024;
    unsigned* g1 = g0 + 1024;
    for (int j = tid; j < 1024; j += 256) {
        if (h0[j]) atomicAdd(&g0[j], h0[j]);
        if (h1[j]) atomicAdd(&g1[j], h1[j]);
    }
}

__global__ void pick3_k(unsigned* __restrict__ ws) {
    __shared__ unsigned sh[256];
    int tid = threadIdx.x; int b = blockIdx.x >> 1, pth = blockIdx.x & 1;
    const unsigned* hist = ws + H3_OFF + (b * 2 + pth) * 1024;
    unsigned r = ws[ST_OFF + b * 4 + pth * 2 + 1];
    unsigned pref = ws[ST_OFF + b * 4 + pth * 2];
    unsigned loc[4], lsum = 0;
    for (int j = 0; j < 4; ++j) { loc[j] = hist[tid * 4 + j]; lsum += loc[j]; }
    sh[tid] = lsum; __syncthreads();
    for (int off = 1; off < 256; off <<= 1) {
        unsigned v = (tid >= off) ? sh[tid - off] : 0u; __syncthreads();
        sh[tid] += v; __syncthreads();
    }
    unsigned base = tid ? sh[tid - 1] : 0u;
    if (r >= base && r < base + lsum) {
        unsigned cacc = base;
        for (int j = 0; j < 4; ++j) {
            if (r < cacc + loc[j]) {
                ws[ST_OFF + b * 4 + pth * 2] = (pref << 10) | (unsigned)(tid * 4 + j);
                break;
            }
            cacc += loc[j];
        }
    }
}

// ---------------- per-block mask counts (wave-chunked, float-key compare) ----------------
__global__ void count_k(const float* __restrict__ cube, unsigned* __restrict__ ws) {
    __shared__ unsigned wcnt_sh[4];
    int tid = threadIdx.x, blk = blockIdx.x;
    int b = blk / 1000, c = blk % 1000;
    int lane = tid & 63, wid = tid >> 6;
    float bval = boundary_from_ws(ws, b);
    // wave w owns elements [c*4096 + w*1024, +1024); lane l, iter t -> float4 at t*64+l
    const float4* p = (const float4*)(cube + (size_t)b * Nn + (size_t)c * 4096 + (size_t)wid * 1024);
    float4 cv[4];
#pragma unroll
    for (int t = 0; t < 4; ++t) cv[t] = p[t * 64 + lane];
    unsigned wcnt = 0;
#pragma unroll
    for (int t = 0; t < 4; ++t) {
        wcnt += (unsigned)__popcll(__ballot(cv[t].x >= bval));
        wcnt += (unsigned)__popcll(__ballot(cv[t].y >= bval));
        wcnt += (unsigned)__popcll(__ballot(cv[t].z >= bval));
        wcnt += (unsigned)__popcll(__ballot(cv[t].w >= bval));
    }
    if (lane == 0) wcnt_sh[wid] = wcnt;
    __syncthreads();
    if (tid == 0) ws[BC_OFF + b * 1000 + c] = wcnt_sh[0] + wcnt_sh[1] + wcnt_sh[2] + wcnt_sh[3];
}

// ---------------- exclusive scan of 1000 block counts per sample ----------------
__global__ void scan_k(unsigned* __restrict__ ws) {
    __shared__ unsigned sh[256];
    int tid = threadIdx.x, b = blockIdx.x;
    unsigned* bc = ws + BC_OFF + b * 1000;
    unsigned loc[4], lsum = 0;
    for (int j = 0; j < 4; ++j) {
        int idx = tid * 4 + j;
        loc[j] = (idx < 1000) ? bc[idx] : 0u;
        lsum += loc[j];
    }
    sh[tid] = lsum; __syncthreads();
    for (int off = 1; off < 256; off <<= 1) {
        unsigned v = (tid >= off) ? sh[tid - off] : 0u; __syncthreads();
        sh[tid] += v; __syncthreads();
    }
    unsigned run = tid ? sh[tid - 1] : 0u;
    for (int j = 0; j < 4; ++j) {
        int idx = tid * 4 + j;
        if (idx < 1000) bc[idx] = run;
        run += loc[j];
    }
    if (tid == 255) ws[CNT_OFF + b] = sh[255];
}

// ---------------- ordered scatter: wave-chunked, 1 barrier, streamed dop ----------------
__device__ __forceinline__ void emit_row(float* __restrict__ out, int b, unsigned k,
                                         int i, float x, float d) {
    size_t row = (size_t)b * Kn + k;
    int xi = i % 320;
    int t = i / 320;
    int yi = t % 320;
    int zi = t / 320;
    float xc = (float)xi / 320.0f * 72.0f;
    float yc = (float)yi / 320.0f * 32.0f;
    float zc = (float)zi / 40.0f * 8.0f;
    float pw = x / 1e13f;
    float dv = d - 1.9326f;
    float* f = out + row * 5;
    f[0] = xc; f[1] = yc; f[2] = zc; f[3] = pw; f[4] = dv;
    float* s = out + OUT_SP + row * 4;
    s[0] = (float)b; s[1] = (float)zi; s[2] = (float)yi; s[3] = (float)xi;
    out[OUT_VAL + row] = 1.0f;
}

__global__ void scatter_k(const float* __restrict__ cube, const float* __restrict__ dop,
                          float* __restrict__ out, const unsigned* __restrict__ ws) {
    __shared__ unsigned wcnt_sh[4];
    int tid = threadIdx.x, blk = blockIdx.x;
    int b = blk / 1000, c = blk % 1000;
    int lane = tid & 63, wid = tid >> 6;
    float bval = boundary_from_ws(ws, b);

    // wave w owns elements [c*4096 + w*1024, +1024); lane l, iter t -> float4 at t*64+l
    size_t chunk = (size_t)b * Nn + (size_t)c * 4096 + (size_t)wid * 1024;
    const float4* pc = (const float4*)(cube + chunk);
    const float4* pd = (const float4*)(dop + chunk);

    // Phase 1: issue all 8 loads per lane up front (max MLP), count via ballots.
    float4 cv[4], dv4[4];
#pragma unroll
    for (int t = 0; t < 4; ++t) { cv[t] = pc[t * 64 + lane]; dv4[t] = pd[t * 64 + lane]; }
    unsigned wcnt = 0;
#pragma unroll
    for (int t = 0; t < 4; ++t) {
        wcnt += (unsigned)__popcll(__ballot(cv[t].x >= bval));
        wcnt += (unsigned)__popcll(__ballot(cv[t].y >= bval));
        wcnt += (unsigned)__popcll(__ballot(cv[t].z >= bval));
        wcnt += (unsigned)__popcll(__ballot(cv[t].w >= bval));
    }
    if (lane == 0) wcnt_sh[wid] = wcnt;
    __syncthreads();

    unsigned wave_base = ws[BC_OFF + b * 1000 + c];
    for (int w = 0; w < wid; ++w) wave_base += wcnt_sh[w];

    unsigned long long lt = (1ull << lane) - 1ull;
    int i0base = c * 4096 + wid * 1024 + lane * 4;

    // Phase 2: ordered ranks from ballots, write rows. Element index = base + lane*4 + q.
#pragma unroll
    for (int t = 0; t < 4; ++t) {
        bool m0 = cv[t].x >= bval, m1 = cv[t].y >= bval, m2 = cv[t].z >= bval, m3 = cv[t].w >= bval;
        unsigned long long b0 = __ballot(m0), b1 = __ballot(m1), b2 = __ballot(m2), b3 = __ballot(m3);
        unsigned s_all = (unsigned)__popcll(b0 & lt) + (unsigned)__popcll(b1 & lt)
                       + (unsigned)__popcll(b2 & lt) + (unsigned)__popcll(b3 & lt);
        unsigned base_l = wave_base + s_all;
        int i0 = i0base + t * 256;
        if (m0) emit_row(out, b, base_l, i0 + 0, cv[t].x, dv4[t].x);
        base_l += (unsigned)m0;
        if (m1) emit_row(out, b, base_l, i0 + 1, cv[t].y, dv4[t].y);
        base_l += (unsigned)m1;
        if (m2) emit_row(out, b, base_l, i0 + 2, cv[t].z, dv4[t].z);
        base_l += (unsigned)m2;
        if (m3) emit_row(out, b, base_l, i0 + 3, cv[t].w, dv4[t].w);
        wave_base += (unsigned)__popcll(b0) + (unsigned)__popcll(b1)
                   + (unsigned)__popcll(b2) + (unsigned)__popcll(b3);
    }
}

// ---------------- zero-fill invalid tail rows (output poisoned each launch) ----------------
__global__ void fill_k(float* __restrict__ out, const unsigned* __restrict__ ws) {
    int g = blockIdx.x * 256 + threadIdx.x;
    if (g >= Bn * Kn) return;
    int b = g / Kn;
    int k = g - b * Kn;
    if ((unsigned)k >= ws[CNT_OFF + b]) {
        size_t row = (size_t)g;
        float* f = out + row * 5;
        f[0] = 0.f; f[1] = 0.f; f[2] = 0.f; f[3] = 0.f; f[4] = 0.f;
        float* s = out + OUT_SP + row * 4;
        s[0] = 0.f; s[1] = 0.f; s[2] = 0.f; s[3] = 0.f;
        out[OUT_VAL + row] = 0.f;
    }
}

extern "C" void kernel_launch(void* const* d_in, const int* in_sizes, int n_in,
                              void* d_out, int out_size, void* d_ws, size_t ws_size,
                              hipStream_t stream) {
    const float* cube = (const float*)d_in[0];
    const float* dop = (const float*)d_in[1];
    float* out = (float*)d_out;
    unsigned* ws = (unsigned*)d_ws;

    // zero the histogram region only (state/bc/cnt are fully overwritten each call)
    hipMemsetAsync(d_ws, 0, 32768 * sizeof(unsigned), stream);

    hipLaunchKernelGGL(hist1_k, dim3(Bn * 250), dim3(256), 0, stream, cube, ws);
    hipLaunchKernelGGL(pick1_k, dim3(Bn), dim3(256), 0, stream, ws);
    hipLaunchKernelGGL(hist2_k, dim3(Bn * 250), dim3(256), 0, stream, cube, ws);
    hipLaunchKernelGGL(pick2_k, dim3(Bn * 2), dim3(256), 0, stream, ws);
    hipLaunchKernelGGL(hist3_k, dim3(Bn * 250), dim3(256), 0, stream, cube, ws);
    hipLaunchKernelGGL(pick3_k, dim3(Bn * 2), dim3(256), 0, stream, ws);
    hipLaunchKernelGGL(count_k, dim3(Bn * 1000), dim3(256), 0, stream, cube, ws);
    hipLaunchKernelGGL(scan_k, dim3(Bn), dim3(256), 0, stream, ws);
    hipLaunchKernelGGL(scatter_k, dim3(Bn * 1000), dim3(256), 0, stream, cube, dop, out, ws);
    hipLaunchKernelGGL(fill_k, dim3((Bn * Kn + 255) / 256), dim3(256), 0, stream, out, ws);
}